// Round 8
// baseline (131.147 us; speedup 1.0000x reference)
//
#include <hip/hip_runtime.h>
#include <math.h>
#include <stdint.h>

#define IMGS 64
#define HWDIM 512
#define KLEN 31
#define RAD 15
#define EPSV 1e-3f
#define MM_STRIDE 32   // ints per image slot (one 128B cache line each)

// ws layout (floats):
//   [0..31)     : separable weights s[i]  (kernel[i][j] = s_i*s_j)
//   [32..2080)  : per-image min/max int bits, 32-int stride
// d_out carries the pre-norm conv result, normalized in place by final_k.

typedef __attribute__((address_space(3))) uint8_t  lds_u8;
typedef const __attribute__((address_space(1))) uint8_t g_u8;

__global__ __launch_bounds__(128) void init_k(const float* __restrict__ gk,
                                              float* __restrict__ w,
                                              int* __restrict__ mm) {
    int t = threadIdx.x;
    if (t < KLEN) w[t] = sqrtf(gk[t * KLEN + t]);   // diag of s_i*s_j = s_i^2
    if (t < IMGS) { mm[t * MM_STRIDE] = 0x7F800000; mm[t * MM_STRIDE + 1] = 0; }
}

// Fused separable 31x31 conv per 64x64 output tile.
// Stage: global_load_lds DMA of raw 94x96 attn tile (x-halo included).
// Pass 1: clamp + zero-fixup in LDS (each value touched once).
// Phase A: horizontal conv LDS->LDS (94x64 intermediate).
// Phase B: vertical conv from LDS -> pre-norm out + per-image min/max.
__global__ __launch_bounds__(256) void conv_k(const float* __restrict__ attn,
                                              float* __restrict__ out,
                                              const float* __restrict__ wg,
                                              int* __restrict__ mm) {
    __shared__ float raw[2304 * 4];              // 94x96 + pad = 36.9 KB
    __shared__ float inter[94 * 64];             // 23.5 KB
    __shared__ float smin[4], smax[4];
    const int t = threadIdx.x;
    const int img = blockIdx.z;
    const int x0 = blockIdx.x << 6;
    const int y0 = blockIdx.y << 6;
    const float* src = attn + ((size_t)img << 18);

    // ---- stage: 2256 float4 items (94 rows x 24 f4) + 48 pad items ----
    // item i -> raw[i*4 .. i*4+3] ; global (y0-15+i/24, x0-16 + (i%24)*4)
    // addresses clamped into the image; OOB slots zeroed in pass 1.
#pragma unroll
    for (int it = 0; it < 9; ++it) {
        const int i  = t + it * 256;
        const int ic = i < 2255 ? i : 2255;
        const int r  = ic / 24;
        const int c4 = ic - r * 24;
        int y  = y0 - RAD + r;
        y = y < 0 ? 0 : (y > HWDIM - 1 ? HWDIM - 1 : y);
        int x4 = (x0 >> 2) - 4 + c4;
        x4 = x4 < 0 ? 0 : (x4 > 127 ? 127 : x4);
        const float* gp = src + (size_t)y * HWDIM + (x4 << 2);
        __builtin_amdgcn_global_load_lds((g_u8*)gp, (lds_u8*)&raw[i * 4], 16, 0, 0);
    }
    __syncthreads();                             // drains vmcnt

    // ---- pass 1: clamp to [0,1], zero the halo-OOB slots ----
#pragma unroll
    for (int it = 0; it < 9; ++it) {
        const int i = t + it * 256;
        if (i < 2256) {
            const int r  = i / 24;
            const int c4 = i - r * 24;
            const int y  = y0 - RAD + r;
            const int x4 = (x0 >> 2) - 4 + c4;
            const bool valid = ((unsigned)y < HWDIM) && ((unsigned)x4 < 128);
            float4 v = *(float4*)&raw[i * 4];
            float4 o;
            o.x = valid ? fminf(fmaxf(v.x, 0.f), 1.f) : 0.f;
            o.y = valid ? fminf(fmaxf(v.y, 0.f), 1.f) : 0.f;
            o.z = valid ? fminf(fmaxf(v.z, 0.f), 1.f) : 0.f;
            o.w = valid ? fminf(fmaxf(v.w, 0.f), 1.f) : 0.f;
            *(float4*)&raw[i * 4] = o;
        }
    }
    __syncthreads();

    // ---- phase A: hconv. item (r, cg): raw[r][4cg..4cg+39] -> inter[r][4cg..+3]
#pragma unroll
    for (int it = 0; it < 6; ++it) {
        const int i = t + it * 256;
        if (i < 94 * 16) {
            const int r  = i >> 4;
            const int cg = i & 15;
            const float* rb = &raw[(r * 24 + cg) * 4];   // raw[r][4cg]
            float vv[40];
#pragma unroll
            for (int m = 0; m < 10; ++m) {
                const float4 q = *(const float4*)(rb + 4 * m);
                vv[4 * m + 0] = q.x; vv[4 * m + 1] = q.y;
                vv[4 * m + 2] = q.z; vv[4 * m + 3] = q.w;
            }
            float4 o;
            float* op = &o.x;
#pragma unroll
            for (int s = 0; s < 4; ++s) {
                float a = 0.f;
#pragma unroll
                for (int k = 0; k < KLEN; ++k) a += vv[1 + s + k] * wg[k];
                op[s] = a;
            }
            *(float4*)&inter[r * 64 + (cg << 2)] = o;
        }
    }
    __syncthreads();

    // ---- phase B: vconv, each thread owns a 4-col x 4-row patch ----
    const int tx = t & 15;
    const int ty = t >> 4;
    float4 acc[4];
#pragma unroll
    for (int i = 0; i < 4; ++i) acc[i] = make_float4(0.f, 0.f, 0.f, 0.f);
#pragma unroll
    for (int k = 0; k < 34; ++k) {
        const float4 v = *(const float4*)&inter[((ty << 2) + k) * 64 + (tx << 2)];
#pragma unroll
        for (int i = 0; i < 4; ++i) {
            const int j = k - i;                 // weight index, compile-time
            if (j >= 0 && j < KLEN) {
                const float w = wg[j];
                acc[i].x += v.x * w;
                acc[i].y += v.y * w;
                acc[i].z += v.z * w;
                acc[i].w += v.w * w;
            }
        }
    }
    float* dst = out + ((size_t)img << 18);
    float lmin = INFINITY, lmax = -INFINITY;
#pragma unroll
    for (int i = 0; i < 4; ++i) {
        *(float4*)&dst[(size_t)(y0 + (ty << 2) + i) * HWDIM + x0 + (tx << 2)] = acc[i];
        lmin = fminf(lmin, fminf(fminf(acc[i].x, acc[i].y), fminf(acc[i].z, acc[i].w)));
        lmax = fmaxf(lmax, fmaxf(fmaxf(acc[i].x, acc[i].y), fmaxf(acc[i].z, acc[i].w)));
    }
    // wave butterfly -> block LDS reduce -> one atomic pair per block
#pragma unroll
    for (int off = 1; off < 64; off <<= 1) {
        lmin = fminf(lmin, __shfl_xor(lmin, off, 64));
        lmax = fmaxf(lmax, __shfl_xor(lmax, off, 64));
    }
    const int lane = t & 63, wid = t >> 6;
    if (lane == 0) { smin[wid] = lmin; smax[wid] = lmax; }
    __syncthreads();
    if (t == 0) {
        float bmin = fminf(fminf(smin[0], smin[1]), fminf(smin[2], smin[3]));
        float bmax = fmaxf(fmaxf(smax[0], smax[1]), fmaxf(smax[2], smax[3]));
        // all values >= 0 -> float ordering == int-bits ordering
        atomicMin(&mm[img * MM_STRIDE], __float_as_int(bmin));
        atomicMax(&mm[img * MM_STRIDE + 1], __float_as_int(bmax));
    }
}

// out = max((out - mn) / max(mx - mn, eps), clip(attn,0,1)), in place.
__global__ __launch_bounds__(256) void final_k(const float* __restrict__ attn,
                                               float* __restrict__ out,
                                               const int* __restrict__ mm) {
    const int img = blockIdx.x >> 6;             // 64 blocks of 4096 elems/image
    const float mn = __int_as_float(mm[img * MM_STRIDE]);
    const float mx = __int_as_float(mm[img * MM_STRIDE + 1]);
    const float inv = 1.0f / fmaxf(mx - mn, EPSV);
    const size_t base0 = ((size_t)blockIdx.x << 12) + ((size_t)threadIdx.x << 2);
#pragma unroll
    for (int h = 0; h < 4; ++h) {
        const size_t base = base0 + (size_t)h * 1024;
        float4 s = *(const float4*)(out + base);
        float4 a = *(const float4*)(attn + base);
        float4 o;
        o.x = fmaxf((s.x - mn) * inv, fminf(fmaxf(a.x, 0.f), 1.f));
        o.y = fmaxf((s.y - mn) * inv, fminf(fmaxf(a.y, 0.f), 1.f));
        o.z = fmaxf((s.z - mn) * inv, fminf(fmaxf(a.z, 0.f), 1.f));
        o.w = fmaxf((s.w - mn) * inv, fminf(fmaxf(a.w, 0.f), 1.f));
        *(float4*)(out + base) = o;
    }
}

extern "C" void kernel_launch(void* const* d_in, const int* in_sizes, int n_in,
                              void* d_out, int out_size, void* d_ws, size_t ws_size,
                              hipStream_t stream) {
    const float* attn = (const float*)d_in[0];
    const float* gk   = (const float*)d_in[1];
    float* out  = (float*)d_out;
    float* wsf  = (float*)d_ws;
    float* w1d  = wsf;
    int*   mm   = (int*)(wsf + 32);

    init_k<<<1, 128, 0, stream>>>(gk, w1d, mm);
    conv_k<<<dim3(8, 8, IMGS), dim3(256), 0, stream>>>(attn, out, w1d, mm);
    final_k<<<IMGS * HWDIM * HWDIM / 4096, 256, 0, stream>>>(attn, out, mm);
}

// Round 9
// 87.929 us; speedup vs baseline: 1.4915x; 1.4915x over previous
//
#include <hip/hip_runtime.h>
#include <math.h>

#define IMGS 64
#define HWDIM 512
#define KLEN 31
#define RAD 15
#define EPSV 1e-3f
#define MM_STRIDE 32   // ints per image slot (one 128B cache line each)

// ws layout (floats):
//   [0..31)     : separable weights s[i]  (kernel[i][j] = s_i*s_j)
//   [32..2080)  : per-image min/max int bits, 32-int stride
// d_out carries the pre-norm conv result, normalized in place by final_k.

__global__ __launch_bounds__(128) void init_k(const float* __restrict__ gk,
                                              float* __restrict__ w,
                                              int* __restrict__ mm) {
    int t = threadIdx.x;
    if (t < KLEN) w[t] = sqrtf(gk[t * KLEN + t]);   // diag of s_i*s_j = s_i^2
    if (t < IMGS) { mm[t * MM_STRIDE] = 0x7F800000; mm[t * MM_STRIDE + 1] = 0; }
}

// Fused separable 31x31 conv per 64x64 output tile.
// Phase A: hconv with double-buffered register prefetch (9 loads in flight
//          while computing the previous item) -> LDS inter[94][64].
// Phase B: vconv from LDS -> pre-norm out + per-image min/max atomics.
__global__ __launch_bounds__(256) void conv_k(const float* __restrict__ attn,
                                              float* __restrict__ out,
                                              const float* __restrict__ wg,
                                              int* __restrict__ mm) {
    __shared__ float inter[94 * 64];             // 23.5 KB
    __shared__ float smin[4], smax[4];
    const int t = threadIdx.x;
    const int img = blockIdx.z;
    const int x0 = blockIdx.x << 6;
    const int y0 = blockIdx.y << 6;
    const float* src = attn + ((size_t)img << 18);
    const int gbase = (x0 >> 2) - 4;             // leftmost f4 group (may be <0)

    // ---- phase A: 1504 items (94 rows x 16 col-groups), 6 groups/thread ----
    // LOAD(g): 9 unconditional float4 loads, addresses clamped into the image.
    // COMPUTE(g): clamp values / zero OOB slots, 124 FMA, write inter.
#define LOADG(G, BUF)                                                          \
    {                                                                          \
        const int i  = t + (G) * 256;                                          \
        const int r  = i >> 4;                                                 \
        const int cg = i & 15;                                                 \
        int y = y0 - RAD + r;                                                  \
        y = y < 0 ? 0 : (y > HWDIM - 1 ? HWDIM - 1 : y);                       \
        const float4* row = (const float4*)(src + ((size_t)y << 9));           \
        const int base = gbase + cg;                                           \
        _Pragma("unroll")                                                      \
        for (int m = 0; m < 9; ++m) {                                          \
            int g4 = base + m;                                                 \
            g4 = g4 < 0 ? 0 : (g4 > 127 ? 127 : g4);                           \
            BUF[m] = row[g4];                                                  \
        }                                                                      \
    }
#define COMPG(G, BUF)                                                          \
    {                                                                          \
        const int i = t + (G) * 256;                                           \
        if (i < 1504) {                                                        \
            const int r  = i >> 4;                                             \
            const int cg = i & 15;                                             \
            const int y  = y0 - RAD + r;                                       \
            const bool vy = (unsigned)y < HWDIM;                               \
            const int base = gbase + cg;                                       \
            float c[36];                                                       \
            _Pragma("unroll")                                                  \
            for (int m = 0; m < 9; ++m) {                                      \
                const bool vx = vy && ((unsigned)(base + m) < 128);            \
                c[4 * m + 0] = vx ? fminf(fmaxf(BUF[m].x, 0.f), 1.f) : 0.f;    \
                c[4 * m + 1] = vx ? fminf(fmaxf(BUF[m].y, 0.f), 1.f) : 0.f;    \
                c[4 * m + 2] = vx ? fminf(fmaxf(BUF[m].z, 0.f), 1.f) : 0.f;    \
                c[4 * m + 3] = vx ? fminf(fmaxf(BUF[m].w, 0.f), 1.f) : 0.f;    \
            }                                                                  \
            float4 o;                                                          \
            float* op = &o.x;                                                  \
            _Pragma("unroll")                                                  \
            for (int s = 0; s < 4; ++s) {                                      \
                float a = 0.f;                                                 \
                _Pragma("unroll")                                              \
                for (int k = 0; k < KLEN; ++k) a += c[1 + s + k] * wg[k];      \
                op[s] = a;                                                     \
            }                                                                  \
            *(float4*)&inter[r * 64 + (cg << 2)] = o;                          \
        }                                                                      \
    }

    {
        float4 bA[9], bB[9];
        LOADG(0, bA);
        LOADG(1, bB); COMPG(0, bA);
        LOADG(2, bA); COMPG(1, bB);
        LOADG(3, bB); COMPG(2, bA);
        LOADG(4, bA); COMPG(3, bB);
        LOADG(5, bB); COMPG(4, bA);
        COMPG(5, bB);
    }
    __syncthreads();

    // ---- phase B: vconv, each thread owns a 4-col x 4-row patch ----
    const int tx = t & 15;
    const int ty = t >> 4;
    float4 acc[4];
#pragma unroll
    for (int i = 0; i < 4; ++i) acc[i] = make_float4(0.f, 0.f, 0.f, 0.f);
#pragma unroll
    for (int k = 0; k < 34; ++k) {
        const float4 v = *(const float4*)&inter[((ty << 2) + k) * 64 + (tx << 2)];
#pragma unroll
        for (int i = 0; i < 4; ++i) {
            const int j = k - i;                 // weight index, compile-time
            if (j >= 0 && j < KLEN) {
                const float w = wg[j];
                acc[i].x += v.x * w;
                acc[i].y += v.y * w;
                acc[i].z += v.z * w;
                acc[i].w += v.w * w;
            }
        }
    }
    float* dst = out + ((size_t)img << 18);
    float lmin = INFINITY, lmax = -INFINITY;
#pragma unroll
    for (int i = 0; i < 4; ++i) {
        *(float4*)&dst[(size_t)(y0 + (ty << 2) + i) * HWDIM + x0 + (tx << 2)] = acc[i];
        lmin = fminf(lmin, fminf(fminf(acc[i].x, acc[i].y), fminf(acc[i].z, acc[i].w)));
        lmax = fmaxf(lmax, fmaxf(fmaxf(acc[i].x, acc[i].y), fmaxf(acc[i].z, acc[i].w)));
    }
    // wave butterfly -> block LDS reduce -> one atomic pair per block
#pragma unroll
    for (int off = 1; off < 64; off <<= 1) {
        lmin = fminf(lmin, __shfl_xor(lmin, off, 64));
        lmax = fmaxf(lmax, __shfl_xor(lmax, off, 64));
    }
    const int lane = t & 63, wid = t >> 6;
    if (lane == 0) { smin[wid] = lmin; smax[wid] = lmax; }
    __syncthreads();
    if (t == 0) {
        float bmin = fminf(fminf(smin[0], smin[1]), fminf(smin[2], smin[3]));
        float bmax = fmaxf(fmaxf(smax[0], smax[1]), fmaxf(smax[2], smax[3]));
        // all values >= 0 -> float ordering == int-bits ordering
        atomicMin(&mm[img * MM_STRIDE], __float_as_int(bmin));
        atomicMax(&mm[img * MM_STRIDE + 1], __float_as_int(bmax));
    }
}

// out = max((out - mn) / max(mx - mn, eps), clip(attn,0,1)), in place.
__global__ __launch_bounds__(256) void final_k(const float* __restrict__ attn,
                                               float* __restrict__ out,
                                               const int* __restrict__ mm) {
    const int img = blockIdx.x >> 6;             // 64 blocks of 4096 elems/image
    const float mn = __int_as_float(mm[img * MM_STRIDE]);
    const float mx = __int_as_float(mm[img * MM_STRIDE + 1]);
    const float inv = 1.0f / fmaxf(mx - mn, EPSV);
    const size_t base0 = ((size_t)blockIdx.x << 12) + ((size_t)threadIdx.x << 2);
#pragma unroll
    for (int h = 0; h < 4; ++h) {
        const size_t base = base0 + (size_t)h * 1024;
        float4 s = *(const float4*)(out + base);
        float4 a = *(const float4*)(attn + base);
        float4 o;
        o.x = fmaxf((s.x - mn) * inv, fminf(fmaxf(a.x, 0.f), 1.f));
        o.y = fmaxf((s.y - mn) * inv, fminf(fmaxf(a.y, 0.f), 1.f));
        o.z = fmaxf((s.z - mn) * inv, fminf(fmaxf(a.z, 0.f), 1.f));
        o.w = fmaxf((s.w - mn) * inv, fminf(fmaxf(a.w, 0.f), 1.f));
        *(float4*)(out + base) = o;
    }
}

extern "C" void kernel_launch(void* const* d_in, const int* in_sizes, int n_in,
                              void* d_out, int out_size, void* d_ws, size_t ws_size,
                              hipStream_t stream) {
    const float* attn = (const float*)d_in[0];
    const float* gk   = (const float*)d_in[1];
    float* out  = (float*)d_out;
    float* wsf  = (float*)d_ws;
    float* w1d  = wsf;
    int*   mm   = (int*)(wsf + 32);

    init_k<<<1, 128, 0, stream>>>(gk, w1d, mm);
    conv_k<<<dim3(8, 8, IMGS), dim3(256), 0, stream>>>(attn, out, w1d, mm);
    final_k<<<IMGS * HWDIM * HWDIM / 4096, 256, 0, stream>>>(attn, out, mm);
}

// Round 10
// 79.854 us; speedup vs baseline: 1.6423x; 1.1011x over previous
//
#include <hip/hip_runtime.h>
#include <math.h>

#define IMGS 64
#define HWDIM 512
#define KLEN 31
#define RAD 15
#define EPSV 1e-3f
#define MM_STRIDE 32   // ints per image slot (one 128B cache line each)

// ws layout (floats):
//   [0..31)     : separable weights s[i]  (kernel[i][j] = s_i*s_j)
//   [32..2080)  : per-image min/max int bits, 32-int stride
// d_out carries the pre-norm conv result, normalized in place by final_k.

__global__ __launch_bounds__(128) void init_k(const float* __restrict__ gk,
                                              float* __restrict__ w,
                                              int* __restrict__ mm) {
    int t = threadIdx.x;
    if (t < KLEN) w[t] = sqrtf(gk[t * KLEN + t]);   // diag of s_i*s_j = s_i^2
    if (t < IMGS) { mm[t * MM_STRIDE] = 0x7F800000; mm[t * MM_STRIDE + 1] = 0; }
}

// ---- phase A helpers: item = (row r 0..93, quarter q 0..3) -> 16 h-outputs ----
template <bool EDGE>
__device__ __forceinline__ void loadA(int i, const float* __restrict__ src,
                                      int x0, int y0, float4* __restrict__ b) {
    const int r = i >> 2, q = i & 3;
    int y = y0 - RAD + r;
    if (EDGE) y = y < 0 ? 0 : (y > HWDIM - 1 ? HWDIM - 1 : y);
    const float4* row = (const float4*)(src + ((size_t)y << 9));
    const int gb = (x0 >> 2) + (q << 2) - 4;
#pragma unroll
    for (int m = 0; m < 12; ++m) {
        int g = gb + m;
        if (EDGE) g = g < 0 ? 0 : (g > 127 ? 127 : g);
        b[m] = row[g];
    }
}

template <bool EDGE>
__device__ __forceinline__ void compA(int i, int x0, int y0,
                                      const float* __restrict__ wg,
                                      float* __restrict__ inter,
                                      const float4* __restrict__ b) {
    const int r = i >> 2, q = i & 3;
    const int y = y0 - RAD + r;
    const int gb = (x0 >> 2) + (q << 2) - 4;
    const bool vy = !EDGE || ((unsigned)y < HWDIM);
    float vv[48];
#pragma unroll
    for (int m = 0; m < 12; ++m) {
        const bool vx = !EDGE || (vy && ((unsigned)(gb + m) < 128u));
        vv[4 * m + 0] = vx ? fminf(fmaxf(b[m].x, 0.f), 1.f) : 0.f;  // v_med3
        vv[4 * m + 1] = vx ? fminf(fmaxf(b[m].y, 0.f), 1.f) : 0.f;
        vv[4 * m + 2] = vx ? fminf(fmaxf(b[m].z, 0.f), 1.f) : 0.f;
        vv[4 * m + 3] = vx ? fminf(fmaxf(b[m].w, 0.f), 1.f) : 0.f;
    }
    float* dst = &inter[r * 64 + (q << 4)];
#pragma unroll
    for (int d = 0; d < 4; ++d) {
        float4 o;
        float* op = &o.x;
#pragma unroll
        for (int s = 0; s < 4; ++s) {
            const int oc = (d << 2) + s;
            float a = 0.f;
#pragma unroll
            for (int k = 0; k < KLEN; ++k) a += vv[oc + 1 + k] * wg[k];
            op[s] = a;
        }
        *(float4*)(dst + (d << 2)) = o;
    }
}

// Fused separable 31x31 conv per 64x64 output tile.
// Phase A: hconv, 16 outputs/thread-item, all loads issued before compute.
// Phase B: vconv from LDS -> pre-norm out + per-image min/max atomics.
template <bool EDGE>
__device__ __forceinline__ void conv_body(const float* __restrict__ attn,
                                          float* __restrict__ out,
                                          const float* __restrict__ wg,
                                          int* __restrict__ mm,
                                          int img, int x0, int y0,
                                          float* __restrict__ inter,
                                          float* __restrict__ sred) {
    const int t = threadIdx.x;
    const float* src = attn + ((size_t)img << 18);

    {   // ---- phase A: 376 items; thread t owns item t and (t<120) 256+t ----
        float4 bA[12], bB[12];
        const bool hasB = t < 120;
        loadA<EDGE>(t, src, x0, y0, bA);
        if (hasB) loadA<EDGE>(256 + t, src, x0, y0, bB);
        compA<EDGE>(t, x0, y0, wg, inter, bA);
        if (hasB) compA<EDGE>(256 + t, x0, y0, wg, inter, bB);
    }
    __syncthreads();

    // ---- phase B: vconv, each thread owns a 4-col x 4-row patch ----
    const int tx = t & 15;
    const int ty = t >> 4;
    float4 acc[4];
#pragma unroll
    for (int i = 0; i < 4; ++i) acc[i] = make_float4(0.f, 0.f, 0.f, 0.f);
#pragma unroll
    for (int k = 0; k < 34; ++k) {
        const float4 v = *(const float4*)&inter[((ty << 2) + k) * 64 + (tx << 2)];
#pragma unroll
        for (int i = 0; i < 4; ++i) {
            const int j = k - i;                 // weight index, compile-time
            if (j >= 0 && j < KLEN) {
                const float w = wg[j];
                acc[i].x += v.x * w;
                acc[i].y += v.y * w;
                acc[i].z += v.z * w;
                acc[i].w += v.w * w;
            }
        }
    }
    float* dst = out + ((size_t)img << 18);
    float lmin = INFINITY, lmax = -INFINITY;
#pragma unroll
    for (int i = 0; i < 4; ++i) {
        *(float4*)&dst[(size_t)(y0 + (ty << 2) + i) * HWDIM + x0 + (tx << 2)] = acc[i];
        lmin = fminf(lmin, fminf(fminf(acc[i].x, acc[i].y), fminf(acc[i].z, acc[i].w)));
        lmax = fmaxf(lmax, fmaxf(fmaxf(acc[i].x, acc[i].y), fmaxf(acc[i].z, acc[i].w)));
    }
    // wave butterfly -> block LDS reduce -> one atomic pair per block
#pragma unroll
    for (int off = 1; off < 64; off <<= 1) {
        lmin = fminf(lmin, __shfl_xor(lmin, off, 64));
        lmax = fmaxf(lmax, __shfl_xor(lmax, off, 64));
    }
    const int lane = t & 63, wid = t >> 6;
    if (lane == 0) { sred[wid] = lmin; sred[4 + wid] = lmax; }
    __syncthreads();
    if (t == 0) {
        float bmin = fminf(fminf(sred[0], sred[1]), fminf(sred[2], sred[3]));
        float bmax = fmaxf(fmaxf(sred[4], sred[5]), fmaxf(sred[6], sred[7]));
        // all values >= 0 -> float ordering == int-bits ordering
        atomicMin(&mm[img * MM_STRIDE], __float_as_int(bmin));
        atomicMax(&mm[img * MM_STRIDE + 1], __float_as_int(bmax));
    }
}

__global__ __launch_bounds__(256) void conv_k(const float* __restrict__ attn,
                                              float* __restrict__ out,
                                              const float* __restrict__ wg,
                                              int* __restrict__ mm) {
    __shared__ float inter[94 * 64];             // 23.5 KB
    __shared__ float sred[8];
    // XCD swizzle: flat 4096-block grid; XCD k (bid&7) gets 512 contiguous
    // work items = 8 whole images -> halo re-reads stay in that XCD's L2.
    const int sw  = ((blockIdx.x & 7) << 9) + (blockIdx.x >> 3);
    const int img = sw >> 6;
    const int by  = (sw >> 3) & 7;
    const int bx  = sw & 7;
    const int x0 = bx << 6;
    const int y0 = by << 6;
    if (bx == 0 || bx == 7 || by == 0 || by == 7)
        conv_body<true>(attn, out, wg, mm, img, x0, y0, inter, sred);
    else
        conv_body<false>(attn, out, wg, mm, img, x0, y0, inter, sred);
}

// out = max((out - mn) / max(mx - mn, eps), clip(attn,0,1)), in place.
__global__ __launch_bounds__(256) void final_k(const float* __restrict__ attn,
                                               float* __restrict__ out,
                                               const int* __restrict__ mm) {
    const int img = blockIdx.x >> 6;             // 64 blocks of 4096 elems/image
    const float mn = __int_as_float(mm[img * MM_STRIDE]);
    const float mx = __int_as_float(mm[img * MM_STRIDE + 1]);
    const float inv = 1.0f / fmaxf(mx - mn, EPSV);
    const size_t base0 = ((size_t)blockIdx.x << 12) + ((size_t)threadIdx.x << 2);
#pragma unroll
    for (int h = 0; h < 4; ++h) {
        const size_t base = base0 + (size_t)h * 1024;
        float4 s = *(const float4*)(out + base);
        float4 a = *(const float4*)(attn + base);
        float4 o;
        o.x = fmaxf((s.x - mn) * inv, fminf(fmaxf(a.x, 0.f), 1.f));
        o.y = fmaxf((s.y - mn) * inv, fminf(fmaxf(a.y, 0.f), 1.f));
        o.z = fmaxf((s.z - mn) * inv, fminf(fmaxf(a.z, 0.f), 1.f));
        o.w = fmaxf((s.w - mn) * inv, fminf(fmaxf(a.w, 0.f), 1.f));
        *(float4*)(out + base) = o;
    }
}

extern "C" void kernel_launch(void* const* d_in, const int* in_sizes, int n_in,
                              void* d_out, int out_size, void* d_ws, size_t ws_size,
                              hipStream_t stream) {
    const float* attn = (const float*)d_in[0];
    const float* gk   = (const float*)d_in[1];
    float* out  = (float*)d_out;
    float* wsf  = (float*)d_ws;
    float* w1d  = wsf;
    int*   mm   = (int*)(wsf + 32);

    init_k<<<1, 128, 0, stream>>>(gk, w1d, mm);
    conv_k<<<4096, 256, 0, stream>>>(attn, out, w1d, mm);
    final_k<<<IMGS * HWDIM * HWDIM / 4096, 256, 0, stream>>>(attn, out, mm);
}